// Round 11
// baseline (443.275 us; speedup 1.0000x reference)
//
#include <hip/hip_runtime.h>
#include <math.h>

// ODCMemory.update_samples_memory for MI355X (gfx950)
// d_in[0] feature_bank [L,D] f32   d_in[1] label_bank [L] int32
// d_in[2] centroids   [C,D] f32    d_in[3] ind [B] int32
// d_in[4] feature     [B,D] f32
// d_out f32: new_bank [L*D] | new_labels [L] | change_ratio [1]

constexpr int Lb = 500000;
constexpr int Dm = 256;
constexpr int D4 = 64;          // float4 per row
constexpr int Cc = 1024;
constexpr int Bb = 16384;
constexpr float EPSV = 1e-10f;

constexpr int ROWS_BLK = 16;            // rows per classify block
constexpr int GCLS  = Bb / ROWS_BLK;    // 1024 classify blocks
constexpr int GCPY  = 3072;             // copy blocks
constexpr int GMAIN = GCLS + GCPY;      // 4096; bid%4==0 -> classify
constexpr int CHUNK = 10496;            // float4 per copy block (contiguous); 3072*10496 >= 32e6
constexpr int GPRE  = 1024;
constexpr int GPOST = 1024;

__device__ __forceinline__ float wave_sum64(float v) {
#pragma unroll
  for (int off = 32; off > 0; off >>= 1) v += __shfl_xor(v, off);
  return v;
}

// momentum-normalized feature for batch row gb vs bank row bankrow (lane = float4 slice)
__device__ __forceinline__ float4 feat_new_row(const float4* __restrict__ feat4,
                                               const float4* __restrict__ bank4,
                                               int gb, int bankrow, int lane) {
  float4 f = feat4[(size_t)gb * D4 + lane];
  const float ss = wave_sum64(f.x * f.x + f.y * f.y + f.z * f.z + f.w * f.w);
  const float inv1 = 1.0f / (sqrtf(ss) + EPSV);
  const float4 o = bank4[(size_t)bankrow * D4 + lane];
  float4 nw;
  nw.x = 0.5f * o.x + 0.5f * (f.x * inv1);
  nw.y = 0.5f * o.y + 0.5f * (f.y * inv1);
  nw.z = 0.5f * o.z + 0.5f * (f.z * inv1);
  nw.w = 0.5f * o.w + 0.5f * (f.w * inv1);
  const float s2 = wave_sum64(nw.x * nw.x + nw.y * nw.y + nw.z * nw.z + nw.w * nw.w);
  const float inv2 = 1.0f / (sqrtf(s2) + EPSV);
  nw.x *= inv2; nw.y *= inv2; nw.z *= inv2; nw.w *= inv2;
  return nw;
}

// marker clear + count clear + centroid transpose + feat_new precompute
__global__ __launch_bounds__(256)
void k_pre(const float4* __restrict__ feat4, const float4* __restrict__ bank4,
           const int* __restrict__ ind, const float* __restrict__ cent,
           float* __restrict__ centT, float4* __restrict__ fnew4,
           int* __restrict__ marker, int* __restrict__ count) {
  const int tid = threadIdx.x, lane = tid & 63, wv = tid >> 6;
  const int t = blockIdx.x * 256 + tid;
  const int stride = GPRE * 256;
  for (int i = t; i < Lb; i += stride) marker[i] = -1;
  for (int i = t; i < Cc * Dm; i += stride) {
    const int d = i >> 10, c = i & (Cc - 1);
    centT[i] = cent[c * Dm + d];          // centT[d][c]; coalesced write
  }
  if (t == 0) *count = 0;
  const int w = blockIdx.x * 4 + wv;      // 4096 waves, 4 rows each
  for (int b = w; b < Bb; b += GPRE * 4)
    fnew4[(size_t)b * D4 + lane] = feat_new_row(feat4, bank4, b, ind[b], lane);
}

__global__ void k_mark(const int* __restrict__ ind, int* __restrict__ marker) {
  const int b = blockIdx.x * blockDim.x + threadIdx.x;
  if (b < Bb) atomicMax(&marker[ind[b]], b);
}

__global__ __launch_bounds__(256)
void k_main(const float4* __restrict__ bank4, const float4* __restrict__ centT4,
            const float4* __restrict__ fnew4, const int* __restrict__ ind,
            const int* __restrict__ label_bank,
            int* __restrict__ newlabel, int* __restrict__ count,
            float4* __restrict__ out4) {
  const int tid  = threadIdx.x;
  const int lane = tid & 63;
  const int wv   = tid >> 6;
  const int bid  = blockIdx.x;

  if (bid % 4 == 0) {
    // ---- classify (R8 structure): 16 rows x 1024 cents; wave-pair owns 8 rows,
    //      128 threads own 8 cents each.
    __shared__ float4 fs[ROWS_BLK][D4];      // 16 KB feat tile
    __shared__ float  redv[ROWS_BLK][2];
    __shared__ int    redc[ROWS_BLK][2];
    const int cls = bid / 4;                 // 0..1023
    const int b0  = cls * ROWS_BLK;
    const int wp  = wv >> 1;
    const int cth = tid & 127;               // cent-thread 0..127
    const int c0  = cth * 8;

    for (int k = tid; k < ROWS_BLK * D4; k += 256)
      ((float4*)fs)[k] = fnew4[(size_t)b0 * D4 + k];
    __syncthreads();

    float4 a0[8], a1[8];
#pragma unroll
    for (int r = 0; r < 8; ++r) { a0[r] = make_float4(0,0,0,0); a1[r] = make_float4(0,0,0,0); }

    const float4* __restrict__ cvp = centT4 + cth * 2;   // centT4[d*256 + cth*2 (+1)]

    for (int d4 = 0; d4 < D4; ++d4) {
      float4 cva[4], cvb[4];
#pragma unroll
      for (int dd = 0; dd < 4; ++dd) {
        cva[dd] = cvp[(size_t)(d4 * 4 + dd) * 256];
        cvb[dd] = cvp[(size_t)(d4 * 4 + dd) * 256 + 1];
      }
#pragma unroll
      for (int r = 0; r < 8; ++r) {
        const float4 f = fs[wp * 8 + r][d4];             // LDS broadcast
#pragma unroll
        for (int dd = 0; dd < 4; ++dd) {
          const float fv = (dd == 0) ? f.x : (dd == 1) ? f.y : (dd == 2) ? f.z : f.w;
          a0[r].x = fmaf(cva[dd].x, fv, a0[r].x);
          a0[r].y = fmaf(cva[dd].y, fv, a0[r].y);
          a0[r].z = fmaf(cva[dd].z, fv, a0[r].z);
          a0[r].w = fmaf(cva[dd].w, fv, a0[r].w);
          a1[r].x = fmaf(cvb[dd].x, fv, a1[r].x);
          a1[r].y = fmaf(cvb[dd].y, fv, a1[r].y);
          a1[r].z = fmaf(cvb[dd].z, fv, a1[r].z);
          a1[r].w = fmaf(cvb[dd].w, fv, a1[r].w);
        }
      }
    }

    // per-row argmax: fold 8 cents (ascending idx, strict >), cross-lane, cross-half
#pragma unroll
    for (int r = 0; r < 8; ++r) {
      float v = a0[r].x; int c = c0;
      if (a0[r].y > v) { v = a0[r].y; c = c0 + 1; }
      if (a0[r].z > v) { v = a0[r].z; c = c0 + 2; }
      if (a0[r].w > v) { v = a0[r].w; c = c0 + 3; }
      if (a1[r].x > v) { v = a1[r].x; c = c0 + 4; }
      if (a1[r].y > v) { v = a1[r].y; c = c0 + 5; }
      if (a1[r].z > v) { v = a1[r].z; c = c0 + 6; }
      if (a1[r].w > v) { v = a1[r].w; c = c0 + 7; }
#pragma unroll
      for (int off = 32; off > 0; off >>= 1) {
        const float ov = __shfl_xor(v, off);
        const int   oc = __shfl_xor(c, off);
        if (ov > v || (ov == v && oc < c)) { v = ov; c = oc; }
      }
      if (lane == 0) { redv[wp * 8 + r][wv & 1] = v; redc[wp * 8 + r][wv & 1] = c; }
    }
    __syncthreads();
    if (tid < ROWS_BLK) {
      float v = redv[tid][0]; int c = redc[tid][0];
      const float ov = redv[tid][1]; const int oc = redc[tid][1];
      if (ov > v) { v = ov; c = oc; }                    // strict > keeps smaller idx
      const int gb = b0 + tid;
      newlabel[gb] = c;
      if (c != label_bank[ind[gb]]) atomicAdd(count, 1);
    }
  } else {
    // ---- streaming copy: contiguous per-block chunk, 8-deep unroll, plain ld/st ----
    const int cpy = bid - bid / 4 - 1;               // 0..3071
    const size_t n4 = (size_t)Lb * D4;
    size_t base = (size_t)cpy * CHUNK;
    size_t end  = base + CHUNK; if (end > n4) end = n4;
    size_t i = base + tid;
    for (; i + 7 * 256 < end; i += 8 * 256) {
      float4 v0 = bank4[i];
      float4 v1 = bank4[i + 256];
      float4 v2 = bank4[i + 2 * 256];
      float4 v3 = bank4[i + 3 * 256];
      float4 v4 = bank4[i + 4 * 256];
      float4 v5 = bank4[i + 5 * 256];
      float4 v6 = bank4[i + 6 * 256];
      float4 v7 = bank4[i + 7 * 256];
      out4[i]           = v0;
      out4[i + 256]     = v1;
      out4[i + 2 * 256] = v2;
      out4[i + 3 * 256] = v3;
      out4[i + 4 * 256] = v4;
      out4[i + 5 * 256] = v5;
      out4[i + 6 * 256] = v6;
      out4[i + 7 * 256] = v7;
    }
    for (; i < end; i += 256) out4[i] = bank4[i];
  }
}

// winner rows from fnew, labels, ratio
__global__ __launch_bounds__(256)
void k_post(const float4* __restrict__ fnew4, const int* __restrict__ ind,
            const int* __restrict__ marker, const int* __restrict__ newlabel,
            const int* __restrict__ label_bank, const int* __restrict__ count,
            float4* __restrict__ out4, float* __restrict__ out_lab,
            float* __restrict__ out_ratio) {
  const int tid = threadIdx.x, lane = tid & 63, wv = tid >> 6;
  const int t = blockIdx.x * 256 + tid;
  const int stride = GPOST * 256;
  for (int i = t; i < Lb; i += stride) {
    const int m = marker[i];
    out_lab[i] = (float)(m >= 0 ? newlabel[m] : label_bank[i]);
  }
  const int w = blockIdx.x * 4 + wv;
  for (int b = w; b < Bb; b += GPOST * 4) {
    const int r = ind[b];
    if (marker[r] == b) out4[(size_t)r * D4 + lane] = fnew4[(size_t)b * D4 + lane];
  }
  if (t == 0) *out_ratio = (float)(*count) / (float)Bb;
}

extern "C" void kernel_launch(void* const* d_in, const int* in_sizes, int n_in,
                              void* d_out, int out_size, void* d_ws, size_t ws_size,
                              hipStream_t stream) {
  const float* bank       = (const float*)d_in[0];
  const int*   label_bank = (const int*)  d_in[1];
  const float* cent       = (const float*)d_in[2];
  const int*   ind        = (const int*)  d_in[3];
  const float* feat       = (const float*)d_in[4];
  float* out = (float*)d_out;

  int*   marker   = (int*)d_ws;                  // [Lb]
  int*   newlabel = marker + Lb;                 // [Bb]
  int*   count    = newlabel + Bb;               // [1]
  float* centT    = (float*)(count + 1);         // [Dm*Cc]  1 MB
  float* fnew     = centT + (size_t)Dm * Cc;     // [Bb*Dm] 16 MB

  float* out_lab   = out + (size_t)Lb * Dm;
  float* out_ratio = out_lab + Lb;

  k_pre <<<GPRE, 256, 0, stream>>>((const float4*)feat, (const float4*)bank, ind,
                                   cent, centT, (float4*)fnew, marker, count);
  k_mark<<<Bb / 256, 256, 0, stream>>>(ind, marker);
  k_main<<<GMAIN, 256, 0, stream>>>((const float4*)bank, (const float4*)centT,
                                    (const float4*)fnew, ind, label_bank,
                                    newlabel, count, (float4*)out);
  k_post<<<GPOST, 256, 0, stream>>>((const float4*)fnew, ind, marker, newlabel,
                                    label_bank, count, (float4*)out, out_lab, out_ratio);
}

// Round 12
// 359.869 us; speedup vs baseline: 1.2318x; 1.2318x over previous
//
#include <hip/hip_runtime.h>
#include <math.h>

// ODCMemory.update_samples_memory for MI355X (gfx950)
// d_in[0] feature_bank [L,D] f32   d_in[1] label_bank [L] int32
// d_in[2] centroids   [C,D] f32    d_in[3] ind [B] int32
// d_in[4] feature     [B,D] f32
// d_out f32: new_bank [L*D] | new_labels [L] | change_ratio [1]

constexpr int Lb = 500000;
constexpr int Dm = 256;
constexpr int D4 = 64;          // float4 per row
constexpr int Cc = 1024;
constexpr int Bb = 16384;
constexpr float EPSV = 1e-10f;

constexpr int ROWS_BLK = 16;            // rows per classify block
constexpr int GCLS  = Bb / ROWS_BLK;    // 1024 classify blocks
constexpr int GMAIN = 2048;             // total blocks; bid<GCLS classify first, all copy
constexpr int CHUNK4 = 16384;           // float4 per copy chunk (256 KB)
constexpr int NCHUNK = ((int)((size_t)Lb * D4 + CHUNK4 - 1) / CHUNK4);  // 1954
constexpr int GPRE  = 1024;
constexpr int GPOST = 1024;

typedef float vfloat4 __attribute__((ext_vector_type(4)));  // native vec for NT ops

__device__ __forceinline__ float wave_sum64(float v) {
#pragma unroll
  for (int off = 32; off > 0; off >>= 1) v += __shfl_xor(v, off);
  return v;
}

// momentum-normalized feature for batch row gb vs bank row bankrow (lane = float4 slice)
__device__ __forceinline__ float4 feat_new_row(const float4* __restrict__ feat4,
                                               const float4* __restrict__ bank4,
                                               int gb, int bankrow, int lane) {
  float4 f = feat4[(size_t)gb * D4 + lane];
  const float ss = wave_sum64(f.x * f.x + f.y * f.y + f.z * f.z + f.w * f.w);
  const float inv1 = 1.0f / (sqrtf(ss) + EPSV);
  const float4 o = bank4[(size_t)bankrow * D4 + lane];
  float4 nw;
  nw.x = 0.5f * o.x + 0.5f * (f.x * inv1);
  nw.y = 0.5f * o.y + 0.5f * (f.y * inv1);
  nw.z = 0.5f * o.z + 0.5f * (f.z * inv1);
  nw.w = 0.5f * o.w + 0.5f * (f.w * inv1);
  const float s2 = wave_sum64(nw.x * nw.x + nw.y * nw.y + nw.z * nw.z + nw.w * nw.w);
  const float inv2 = 1.0f / (sqrtf(s2) + EPSV);
  nw.x *= inv2; nw.y *= inv2; nw.z *= inv2; nw.w *= inv2;
  return nw;
}

// marker clear + counters + centroid transpose + feat_new precompute
__global__ __launch_bounds__(256)
void k_pre(const float4* __restrict__ feat4, const float4* __restrict__ bank4,
           const int* __restrict__ ind, const float* __restrict__ cent,
           float* __restrict__ centT, float4* __restrict__ fnew4,
           int* __restrict__ marker, int* __restrict__ count, int* __restrict__ steal) {
  const int tid = threadIdx.x, lane = tid & 63, wv = tid >> 6;
  const int t = blockIdx.x * 256 + tid;
  const int stride = GPRE * 256;
  for (int i = t; i < Lb; i += stride) marker[i] = -1;
  for (int i = t; i < Cc * Dm; i += stride) {
    const int d = i >> 10, c = i & (Cc - 1);
    centT[i] = cent[c * Dm + d];          // centT[d][c]; coalesced write
  }
  if (t == 0) { *count = 0; *steal = 0; }
  const int w = blockIdx.x * 4 + wv;      // 4096 waves, 4 rows each
  for (int b = w; b < Bb; b += GPRE * 4)
    fnew4[(size_t)b * D4 + lane] = feat_new_row(feat4, bank4, b, ind[b], lane);
}

__global__ void k_mark(const int* __restrict__ ind, int* __restrict__ marker) {
  const int b = blockIdx.x * blockDim.x + threadIdx.x;
  if (b < Bb) atomicMax(&marker[ind[b]], b);
}

__global__ __launch_bounds__(256)
void k_main(const float4* __restrict__ bank4, const float4* __restrict__ centT4,
            const float4* __restrict__ fnew4, const int* __restrict__ ind,
            const int* __restrict__ label_bank,
            int* __restrict__ newlabel, int* __restrict__ count,
            int* __restrict__ steal, float4* __restrict__ out4) {
  __shared__ float4 fs[ROWS_BLK][D4];      // 16 KB feat tile (classify only)
  __shared__ float  redv[ROWS_BLK][2];
  __shared__ int    redc[ROWS_BLK][2];
  __shared__ int    sm_chunk;
  const int tid  = threadIdx.x;
  const int lane = tid & 63;
  const int wv   = tid >> 6;
  const int bid  = blockIdx.x;

  if (bid < GCLS) {
    // ---- classify (R8 structure): 16 rows x 1024 cents; wave-pair owns 8 rows,
    //      128 threads own 8 cents each.
    const int b0  = bid * ROWS_BLK;
    const int wp  = wv >> 1;
    const int cth = tid & 127;               // cent-thread 0..127
    const int c0  = cth * 8;

    for (int k = tid; k < ROWS_BLK * D4; k += 256)
      ((float4*)fs)[k] = fnew4[(size_t)b0 * D4 + k];
    __syncthreads();

    float4 a0[8], a1[8];
#pragma unroll
    for (int r = 0; r < 8; ++r) { a0[r] = make_float4(0,0,0,0); a1[r] = make_float4(0,0,0,0); }

    const float4* __restrict__ cvp = centT4 + cth * 2;   // centT4[d*256 + cth*2 (+1)]

    for (int d4 = 0; d4 < D4; ++d4) {
      float4 cva[4], cvb[4];
#pragma unroll
      for (int dd = 0; dd < 4; ++dd) {
        cva[dd] = cvp[(size_t)(d4 * 4 + dd) * 256];
        cvb[dd] = cvp[(size_t)(d4 * 4 + dd) * 256 + 1];
      }
#pragma unroll
      for (int r = 0; r < 8; ++r) {
        const float4 f = fs[wp * 8 + r][d4];             // LDS broadcast
#pragma unroll
        for (int dd = 0; dd < 4; ++dd) {
          const float fv = (dd == 0) ? f.x : (dd == 1) ? f.y : (dd == 2) ? f.z : f.w;
          a0[r].x = fmaf(cva[dd].x, fv, a0[r].x);
          a0[r].y = fmaf(cva[dd].y, fv, a0[r].y);
          a0[r].z = fmaf(cva[dd].z, fv, a0[r].z);
          a0[r].w = fmaf(cva[dd].w, fv, a0[r].w);
          a1[r].x = fmaf(cvb[dd].x, fv, a1[r].x);
          a1[r].y = fmaf(cvb[dd].y, fv, a1[r].y);
          a1[r].z = fmaf(cvb[dd].z, fv, a1[r].z);
          a1[r].w = fmaf(cvb[dd].w, fv, a1[r].w);
        }
      }
    }

    // per-row argmax: fold 8 cents (ascending idx, strict >), cross-lane, cross-half
#pragma unroll
    for (int r = 0; r < 8; ++r) {
      float v = a0[r].x; int c = c0;
      if (a0[r].y > v) { v = a0[r].y; c = c0 + 1; }
      if (a0[r].z > v) { v = a0[r].z; c = c0 + 2; }
      if (a0[r].w > v) { v = a0[r].w; c = c0 + 3; }
      if (a1[r].x > v) { v = a1[r].x; c = c0 + 4; }
      if (a1[r].y > v) { v = a1[r].y; c = c0 + 5; }
      if (a1[r].z > v) { v = a1[r].z; c = c0 + 6; }
      if (a1[r].w > v) { v = a1[r].w; c = c0 + 7; }
#pragma unroll
      for (int off = 32; off > 0; off >>= 1) {
        const float ov = __shfl_xor(v, off);
        const int   oc = __shfl_xor(c, off);
        if (ov > v || (ov == v && oc < c)) { v = ov; c = oc; }
      }
      if (lane == 0) { redv[wp * 8 + r][wv & 1] = v; redc[wp * 8 + r][wv & 1] = c; }
    }
    __syncthreads();
    if (tid < ROWS_BLK) {
      float v = redv[tid][0]; int c = redc[tid][0];
      const float ov = redv[tid][1]; const int oc = redc[tid][1];
      if (ov > v) { v = ov; c = oc; }                    // strict > keeps smaller idx
      const int gb = b0 + tid;
      newlabel[gb] = c;
      if (c != label_bank[ind[gb]]) atomicAdd(count, 1);
    }
  }

  // ---- work-stealing copy: all blocks pull 256 KB chunks; NT stores ----
  const vfloat4* __restrict__ src = (const vfloat4*)bank4;
  vfloat4* __restrict__ dst = (vfloat4*)out4;
  const size_t n4 = (size_t)Lb * D4;
  for (;;) {
    __syncthreads();
    if (tid == 0) sm_chunk = atomicAdd(steal, 1);
    __syncthreads();
    const int ch = sm_chunk;
    if (ch >= NCHUNK) break;
    const size_t base = (size_t)ch * CHUNK4;
    if (base + CHUNK4 <= n4) {
#pragma unroll
      for (int k = 0; k < 64; k += 8) {
        vfloat4 v0 = src[base + (size_t)(k + 0) * 256 + tid];
        vfloat4 v1 = src[base + (size_t)(k + 1) * 256 + tid];
        vfloat4 v2 = src[base + (size_t)(k + 2) * 256 + tid];
        vfloat4 v3 = src[base + (size_t)(k + 3) * 256 + tid];
        vfloat4 v4 = src[base + (size_t)(k + 4) * 256 + tid];
        vfloat4 v5 = src[base + (size_t)(k + 5) * 256 + tid];
        vfloat4 v6 = src[base + (size_t)(k + 6) * 256 + tid];
        vfloat4 v7 = src[base + (size_t)(k + 7) * 256 + tid];
        __builtin_nontemporal_store(v0, &dst[base + (size_t)(k + 0) * 256 + tid]);
        __builtin_nontemporal_store(v1, &dst[base + (size_t)(k + 1) * 256 + tid]);
        __builtin_nontemporal_store(v2, &dst[base + (size_t)(k + 2) * 256 + tid]);
        __builtin_nontemporal_store(v3, &dst[base + (size_t)(k + 3) * 256 + tid]);
        __builtin_nontemporal_store(v4, &dst[base + (size_t)(k + 4) * 256 + tid]);
        __builtin_nontemporal_store(v5, &dst[base + (size_t)(k + 5) * 256 + tid]);
        __builtin_nontemporal_store(v6, &dst[base + (size_t)(k + 6) * 256 + tid]);
        __builtin_nontemporal_store(v7, &dst[base + (size_t)(k + 7) * 256 + tid]);
      }
    } else {
      for (int k = 0; k < 64; ++k) {
        const size_t i = base + (size_t)k * 256 + tid;
        if (i < n4) __builtin_nontemporal_store(src[i], &dst[i]);
      }
    }
  }
}

// winner rows from fnew, labels, ratio
__global__ __launch_bounds__(256)
void k_post(const float4* __restrict__ fnew4, const int* __restrict__ ind,
            const int* __restrict__ marker, const int* __restrict__ newlabel,
            const int* __restrict__ label_bank, const int* __restrict__ count,
            float4* __restrict__ out4, float* __restrict__ out_lab,
            float* __restrict__ out_ratio) {
  const int tid = threadIdx.x, lane = tid & 63, wv = tid >> 6;
  const int t = blockIdx.x * 256 + tid;
  const int stride = GPOST * 256;
  for (int i = t; i < Lb; i += stride) {
    const int m = marker[i];
    out_lab[i] = (float)(m >= 0 ? newlabel[m] : label_bank[i]);
  }
  const int w = blockIdx.x * 4 + wv;
  for (int b = w; b < Bb; b += GPOST * 4) {
    const int r = ind[b];
    if (marker[r] == b) out4[(size_t)r * D4 + lane] = fnew4[(size_t)b * D4 + lane];
  }
  if (t == 0) *out_ratio = (float)(*count) / (float)Bb;
}

extern "C" void kernel_launch(void* const* d_in, const int* in_sizes, int n_in,
                              void* d_out, int out_size, void* d_ws, size_t ws_size,
                              hipStream_t stream) {
  const float* bank       = (const float*)d_in[0];
  const int*   label_bank = (const int*)  d_in[1];
  const float* cent       = (const float*)d_in[2];
  const int*   ind        = (const int*)  d_in[3];
  const float* feat       = (const float*)d_in[4];
  float* out = (float*)d_out;

  int*   marker   = (int*)d_ws;                  // [Lb]
  int*   newlabel = marker + Lb;                 // [Bb]
  int*   count    = newlabel + Bb;               // [1]
  int*   steal    = count + 1;                   // [1]
  float* centT    = (float*)(steal + 1);         // [Dm*Cc]  1 MB
  float* fnew     = centT + (size_t)Dm * Cc;     // [Bb*Dm] 16 MB

  float* out_lab   = out + (size_t)Lb * Dm;
  float* out_ratio = out_lab + Lb;

  k_pre <<<GPRE, 256, 0, stream>>>((const float4*)feat, (const float4*)bank, ind,
                                   cent, centT, (float4*)fnew, marker, count, steal);
  k_mark<<<Bb / 256, 256, 0, stream>>>(ind, marker);
  k_main<<<GMAIN, 256, 0, stream>>>((const float4*)bank, (const float4*)centT,
                                    (const float4*)fnew, ind, label_bank,
                                    newlabel, count, steal, (float4*)out);
  k_post<<<GPOST, 256, 0, stream>>>((const float4*)fnew, ind, marker, newlabel,
                                    label_bank, count, (float4*)out, out_lab, out_ratio);
}